// Round 11
// baseline (8952.718 us; speedup 1.0000x reference)
//
#include <hip/hip_runtime.h>

#define NUM_ITERS 15
#define BB 2
#define NN 2048
#define QQ 256
#define CHUNKS 16          // colsum n-chunks of 128 rows

// ---------------------------------------------------------------------------
// Numerical contract (matches numpy-fp32 golden; verified absmax 0.00195 —
// LOAD-BEARING, do not relax):
//  - no FMA contraction (pragma clang fp contract(off))
//  - GEMM per output element: single fp32 accumulator, strictly ascending k,
//    round(mul) then round(add), final true division by max(sum,1)
//  - row reductions over q=256: numpy pairwise tree, order replicated exactly
//  - colsum: ascending-n in 16 chunks, combined ascending
//
// R4: gfx950 VGPR max=256; uncapped bounds + big unrolls -> scratch spill.
// R5: 1 wave/SIMD latency-bound under COMPILER scheduling.
// R6: counted waitcnt regions need "memory" clobbers + sched_barrier fences.
// R7: counted-lgkm 4x2/8-wave = 141us = 87% of ~85 B/cyc/CU LDS ceiling.
// R8/R9: 4-wave configs cap ~45 B/cyc regardless of depth. LDS GEMM boxed
//     at 123-141us. Escape = take operands OFF the LDS pipe.
// R10 lesson: do NOT pin large rotating register files in inline-asm tuple
//     constraints (72 VGPRs of "=v" quads under cap 128) — scratch ops from
//     regalloc break counted vmcnt and/or crash. Plain C++ this round.
// ---------------------------------------------------------------------------

typedef float f4v __attribute__((ext_vector_type(4)));
typedef float f2v __attribute__((ext_vector_type(2)));
typedef __attribute__((address_space(3))) const float4 lds_cf4;

// counted-region primitives (R6 lesson), used only by the proven it==0 kernel
#define DSR128(d, a, IMM) asm volatile("ds_read_b128 %0, %1 offset:" #IMM : "=v"(d) : "v"(a) : "memory")
#define DSR64(d, a, IMM)  asm volatile("ds_read_b64 %0, %1 offset:" #IMM  : "=v"(d) : "v"(a) : "memory")
#define LGKM(N)           asm volatile("s_waitcnt lgkmcnt(" #N ")" ::: "memory")

__global__ __launch_bounds__(256) void colsum_part(
    const float* __restrict__ adj, const float* __restrict__ act,
    float* __restrict__ pe0, float* __restrict__ pi0,
    float* __restrict__ pe1, float* __restrict__ pi1)
{
#pragma clang fp contract(off)
    const int b = (int)blockIdx.z;
    const int c = (int)blockIdx.y;
    const int m = (int)blockIdx.x * 256 + (int)threadIdx.x;
    const float* src = adj + (size_t)b * NN * NN;
    const float* ab  = act + (size_t)b * NN;
    float se0 = 0.0f, si0 = 0.0f, se1 = 0.0f, si1 = 0.0f;
    const int n0 = c * (NN / CHUNKS);
    for (int n = n0; n < n0 + NN / CHUNKS; ++n) {
        float x = src[(size_t)n * NN + m];
        float e = (x > 0.5f) ? x : 0.0f;
        float v = 1.0f - x;
        float iv = (v > 0.5f) ? v : 0.0f;
        float av = ab[n];
        se1 = se1 + e;
        si1 = si1 + iv;
        se0 = se0 + e * av;
        si0 = si0 + iv * av;
    }
    size_t o = ((size_t)c * BB + b) * NN + m;
    pe0[o] = se0; pi0[o] = si0; pe1[o] = se1; pi1[o] = si1;
}

__global__ __launch_bounds__(256) void colsum_combine(
    const float* __restrict__ pe0, const float* __restrict__ pi0,
    const float* __restrict__ pe1, const float* __restrict__ pi1,
    float* __restrict__ se0, float* __restrict__ si0,
    float* __restrict__ se1, float* __restrict__ si1)
{
#pragma clang fp contract(off)
    const int i = (int)blockIdx.x * 256 + (int)threadIdx.x;   // 0..BB*NN-1
    float a = 0.0f, bb = 0.0f, cc = 0.0f, dd = 0.0f;
    for (int c = 0; c < CHUNKS; ++c) {
        size_t o = (size_t)c * (BB * NN) + i;
        a  = a  + pe0[o];
        bb = bb + pi0[o];
        cc = cc + pe1[o];
        dd = dd + pi1[o];
    }
    se0[i] = a; si0[i] = bb; se1[i] = cc; si1[i] = dd;
}

// ---------------------------------------------------------------------------
// it==0 path (act present): EXACT R7-proven LDS kernel.
// 64x64 tile, BK=64, 512 thr, 4x2 microtile, dbuf LDS, counted lgkmcnt.
// ---------------------------------------------------------------------------
__global__ __launch_bounds__(512, 2) void gemm_fused(
    const float* __restrict__ adj,
    const float* __restrict__ hsrc,
    const float* act,
    const float* __restrict__ sums,
    const float* h_old,
    float* __restrict__ dst,
    int mode)
{
#pragma clang fp contract(off)
    __shared__ float4 W2[2][64][17];   // [dbuf][kk][16 float4 m-cols +pad] row=272B
    __shared__ float4 H2[2][64][17];

    const int b  = (int)blockIdx.z;
    const int m0 = (int)blockIdx.x * 64;
    const int q0 = (int)blockIdx.y * 64;
    const int tid = (int)threadIdx.x;
    const int tq  = tid & 31;      // q-group: cols q0 + tq*2 .. +1
    const int tm  = tid >> 5;      // m-group: rows m0 + tm*4 .. +3

    const float* adjb = adj + (size_t)b * NN * NN;
    const float* hb   = hsrc + (size_t)b * NN * QQ;
    const float* ab   = (act != 0) ? (act + (size_t)b * NN) : (const float*)0;

    const unsigned wbase = (unsigned)(uintptr_t)(lds_cf4*)&W2[0][0][0] + (unsigned)tm * 16u;
    const unsigned hbase = (unsigned)(uintptr_t)(lds_cf4*)&H2[0][0][0] + (unsigned)tq * 8u;

    float acc[4][2];
    #pragma unroll
    for (int i = 0; i < 4; ++i)
        #pragma unroll
        for (int j = 0; j < 2; ++j)
            acc[i][j] = 0.0f;

    float4 wreg[2], hreg[2];

    auto stage_load = [&](int kbase) {
#pragma clang fp contract(off)
        #pragma unroll
        for (int j = 0; j < 2; ++j) {
            int idx = tid + j * 512;
            int kk  = idx >> 4;
            int seg = idx & 15;
            wreg[j] = *(const float4*)(adjb + (size_t)(kbase + kk) * NN + m0 + seg * 4);
            hreg[j] = *(const float4*)(hb   + (size_t)(kbase + kk) * QQ + q0 + seg * 4);
        }
    };

    auto stage_store = [&](int sbuf, int kbase) {
#pragma clang fp contract(off)
        #pragma unroll
        for (int j = 0; j < 2; ++j) {
            int idx = tid + j * 512;
            int kk  = idx >> 4;
            int seg = idx & 15;
            float4 x = wreg[j];
            float4 w;
            if (mode == 0) {
                w.x = (x.x > 0.5f) ? x.x : 0.0f;
                w.y = (x.y > 0.5f) ? x.y : 0.0f;
                w.z = (x.z > 0.5f) ? x.z : 0.0f;
                w.w = (x.w > 0.5f) ? x.w : 0.0f;
            } else {
                float vx = 1.0f - x.x; w.x = (vx > 0.5f) ? vx : 0.0f;
                float vy = 1.0f - x.y; w.y = (vy > 0.5f) ? vy : 0.0f;
                float vz = 1.0f - x.z; w.z = (vz > 0.5f) ? vz : 0.0f;
                float vw = 1.0f - x.w; w.w = (vw > 0.5f) ? vw : 0.0f;
            }
            if (ab != 0) {
                float av = ab[kbase + kk];
                w.x = w.x * av; w.y = w.y * av; w.z = w.z * av; w.w = w.w * av;
            }
            W2[sbuf][kk][seg] = w;
            H2[sbuf][kk][seg] = hreg[j];
        }
    };

    auto compute = [&](int cbuf) {
#pragma clang fp contract(off)
        __builtin_amdgcn_sched_barrier(0);
        const unsigned wa = wbase + (unsigned)cbuf * 17408u;
        const unsigned ha = hbase + (unsigned)cbuf * 17408u;
        f4v w[2][4];
        f2v h[2][4];
        DSR128(w[0][0], wa, 0);   DSR128(w[0][1], wa, 272);
        DSR128(w[0][2], wa, 544); DSR128(w[0][3], wa, 816);
        DSR64 (h[0][0], ha, 0);   DSR64 (h[0][1], ha, 272);
        DSR64 (h[0][2], ha, 544); DSR64 (h[0][3], ha, 816);
        #pragma unroll
        for (int g = 0; g < 16; ++g) {
            const int s = g & 1, sn = s ^ 1;
            if (g < 15) {
                unsigned awn = wa + (unsigned)((g + 1) * 1088);
                unsigned ahn = ha + (unsigned)((g + 1) * 1088);
                DSR128(w[sn][0], awn, 0);   DSR128(w[sn][1], awn, 272);
                DSR128(w[sn][2], awn, 544); DSR128(w[sn][3], awn, 816);
                DSR64 (h[sn][0], ahn, 0);   DSR64 (h[sn][1], ahn, 272);
                DSR64 (h[sn][2], ahn, 544); DSR64 (h[sn][3], ahn, 816);
                LGKM(8);
            } else {
                LGKM(0);
            }
            __builtin_amdgcn_sched_barrier(0);
            #pragma unroll
            for (int j = 0; j < 4; ++j) {
                f4v wv = w[s][j];
                f2v hv = h[s][j];
                #pragma unroll
                for (int i = 0; i < 4; ++i) {
                    acc[i][0] = acc[i][0] + wv[i] * hv[0];
                    acc[i][1] = acc[i][1] + wv[i] * hv[1];
                }
            }
        }
        __builtin_amdgcn_sched_barrier(0);
    };

    stage_load(0);
    stage_store(0, 0);
    __syncthreads();

    int cur = 0;
    #pragma clang loop unroll(disable)
    for (int k0 = 0; k0 < NN; k0 += 64) {
        const int knext = k0 + 64;
        if (knext < NN) stage_load(knext);
        compute(cur);
        if (knext < NN) {
            stage_store(cur ^ 1, knext);
            __syncthreads();
            cur ^= 1;
        }
    }

    #pragma unroll
    for (int i = 0; i < 4; ++i) {
        int row = m0 + tm * 4 + i;
        float s = sums[b * NN + row];
        if (s < 1.0f) s = 1.0f;
        float v0 = acc[i][0] / s;
        float v1 = acc[i][1] / s;
        size_t g = ((size_t)b * NN + row) * QQ + q0 + tq * 2;
        float2 o;
        if (mode == 0) {
            float2 ho = *(const float2*)(h_old + g);
            o.x = ho.x + v0; o.y = ho.y + v1;
        } else {
            o.x = v0; o.y = v1;
        }
        *(float2*)(dst + g) = o;
    }
}

// ---------------------------------------------------------------------------
// it>0 path (no act): DIRECT register GEMM, zero LDS, PLAIN C++ (R10 lesson).
//   C[m][q] = sum_k thr(adj[k][m]) * hsrc[k][q]   (ascending k)
// 64x64 tile, 512 thr (8 waves = 2/SIMD via grid), 4x2 microtile.
// K = 256 groups of 8 kk; 2 register slots, consume-then-reload (R3-proven
// compiler pipelining; read->use distance = 64 MACs ~ 128 cyc/wave).
// Per-block unique traffic 512 B/kk (W 16x16B broadcast, H 256B shared by
// all 8 waves) -> L1-resident -> VALU-bound (~64-72 cyc/kk/CU, ~60-75us).
// Explicit live set ~116 VGPR under cap 128 (launch_bounds 512,2).
// Threshold recomputed per use: identical ops -> bit-identical chain.
// ---------------------------------------------------------------------------
template<int MODE>
__global__ __launch_bounds__(512, 2) void gemm_direct(
    const float* __restrict__ adj,
    const float* __restrict__ hsrc,
    const float* __restrict__ sums,
    const float* __restrict__ h_old,
    float* __restrict__ dst)
{
#pragma clang fp contract(off)
    const int b  = (int)blockIdx.z;
    const int m0 = (int)blockIdx.x * 64;
    const int q0 = (int)blockIdx.y * 64;
    const int tid = (int)threadIdx.x;
    const int tq  = tid & 31;      // cols q0 + tq*2 .. +1
    const int tm  = tid >> 5;      // rows m0 + tm*4 .. +3

    const float* wcol = adj  + (size_t)b * NN * NN + (m0 + tm * 4);
    const float* hcol = hsrc + (size_t)b * NN * QQ + (q0 + tq * 2);

    float a00 = 0.0f, a01 = 0.0f, a10 = 0.0f, a11 = 0.0f;
    float a20 = 0.0f, a21 = 0.0f, a30 = 0.0f, a31 = 0.0f;

    float4 wA[8], wB[8];
    float2 hA[8], hB[8];

    // load one 8-kk group (k rows 8g..8g+7) into a slot
    auto loadg = [&](int g, float4* w, float2* h) {
#pragma clang fp contract(off)
        const float* wp = wcol + (size_t)(g * 8) * NN;
        const float* hp = hcol + (size_t)(g * 8) * QQ;
        #pragma unroll
        for (int r = 0; r < 8; ++r) {
            w[r] = *(const float4*)(wp + (size_t)r * NN);
            h[r] = *(const float2*)(hp + (size_t)r * QQ);
        }
    };

    // consume one slot: 8 kk ascending, threshold + 8 MACs each
    auto consume = [&](const float4* w, const float2* h) {
#pragma clang fp contract(off)
        #pragma unroll
        for (int r = 0; r < 8; ++r) {
            float4 x = w[r];
            float2 hv = h[r];
            float t0, t1, t2, t3;
            if (MODE == 0) {
                t0 = (x.x > 0.5f) ? x.x : 0.0f;
                t1 = (x.y > 0.5f) ? x.y : 0.0f;
                t2 = (x.z > 0.5f) ? x.z : 0.0f;
                t3 = (x.w > 0.5f) ? x.w : 0.0f;
            } else {
                float v0 = 1.0f - x.x; t0 = (v0 > 0.5f) ? v0 : 0.0f;
                float v1 = 1.0f - x.y; t1 = (v1 > 0.5f) ? v1 : 0.0f;
                float v2 = 1.0f - x.z; t2 = (v2 > 0.5f) ? v2 : 0.0f;
                float v3 = 1.0f - x.w; t3 = (v3 > 0.5f) ? v3 : 0.0f;
            }
            a00 = a00 + t0 * hv.x; a01 = a01 + t0 * hv.y;
            a10 = a10 + t1 * hv.x; a11 = a11 + t1 * hv.y;
            a20 = a20 + t2 * hv.x; a21 = a21 + t2 * hv.y;
            a30 = a30 + t3 * hv.x; a31 = a31 + t3 * hv.y;
        }
    };

    // prologue: groups 0,1
    loadg(0, wA, hA);
    loadg(1, wB, hB);

    // main: 127 iters consume groups 0..253, reload 2..255
    #pragma clang loop unroll(disable)
    for (int g = 0; g < 127; ++g) {
        consume(wA, hA);
        loadg(2 * g + 2, wA, hA);
        consume(wB, hB);
        loadg(2 * g + 3, wB, hB);
    }
    // tail: groups 254, 255
    consume(wA, hA);
    consume(wB, hB);

    // epilogue: true division, optional h_old add, float2 stores
    float accs[4][2] = {{a00, a01}, {a10, a11}, {a20, a21}, {a30, a31}};
    #pragma unroll
    for (int i = 0; i < 4; ++i) {
        int row = m0 + tm * 4 + i;
        float s = sums[b * NN + row];
        if (s < 1.0f) s = 1.0f;
        float v0 = accs[i][0] / s;
        float v1 = accs[i][1] / s;
        size_t g = ((size_t)b * NN + row) * QQ + q0 + tq * 2;
        float2 o;
        if (MODE == 0) {
            float2 ho = *(const float2*)(h_old + g);
            o.x = ho.x + v0; o.y = ho.y + v1;
        } else {
            o.x = v0; o.y = v1;
        }
        *(float2*)(dst + g) = o;
    }
}

// ---------------------------------------------------------------------------
// Projection + relu + L2-normalize, np-fp32-exact, in place on h_io.
// ---------------------------------------------------------------------------
__global__ __launch_bounds__(256) void project_kernel(
    float* h_io, const float* __restrict__ ieff)
{
#pragma clang fp contract(off)
    __shared__ float sp[256];
    __shared__ float sq[256];
    __shared__ float rs[32];
    __shared__ float sc[2];
    const int b = (int)blockIdx.y;
    const int m = (int)blockIdx.x;
    const int t = (int)threadIdx.x;

    size_t gi = ((size_t)b * NN + m) * QQ + t;
    float hv = h_io[gi];
    float ie = ieff[gi];

    sp[t] = hv * ie;
    sq[t] = ie * ie;
    __syncthreads();
    if (t < 32) {
        const float* a = (t < 16) ? sp : sq;
        int j = t & 7;
        int base = (t & 8) ? 128 : 0;
        float r = a[base + j];
        for (int i = 8; i < 128; i += 8) r = r + a[base + i + j];
        rs[t] = r;
    }
    __syncthreads();
    if (t == 0) {
        float d0 = ((rs[0] + rs[1]) + (rs[2] + rs[3])) + ((rs[4] + rs[5]) + (rs[6] + rs[7]));
        float d1 = ((rs[8] + rs[9]) + (rs[10] + rs[11])) + ((rs[12] + rs[13]) + (rs[14] + rs[15]));
        float dot = d0 + d1;
        float u0 = ((rs[16] + rs[17]) + (rs[18] + rs[19])) + ((rs[20] + rs[21]) + (rs[22] + rs[23]));
        float u1 = ((rs[24] + rs[25]) + (rs[26] + rs[27])) + ((rs[28] + rs[29]) + (rs[30] + rs[31]));
        float un = u0 + u1;
        sc[0] = dot / (un + 1e-12f);
    }
    __syncthreads();
    float c = sc[0];
    float tmp = c * ie;
    float h2 = hv - tmp;
    float r = (h2 > 0.0f) ? h2 : 0.0f;
    sp[t] = r * r;
    __syncthreads();
    if (t < 16) {
        int j = t & 7;
        int base = (t & 8) ? 128 : 0;
        float rr = sp[base + j];
        for (int i = 8; i < 128; i += 8) rr = rr + sp[base + i + j];
        rs[t] = rr;
    }
    __syncthreads();
    if (t == 0) {
        float n0 = ((rs[0] + rs[1]) + (rs[2] + rs[3])) + ((rs[4] + rs[5]) + (rs[6] + rs[7]));
        float n1 = ((rs[8] + rs[9]) + (rs[10] + rs[11])) + ((rs[12] + rs[13]) + (rs[14] + rs[15]));
        float nn = n0 + n1;
        float den = (float)sqrt((double)nn);
        if (den < 1e-8f) den = 1e-8f;
        sc[1] = den;
    }
    __syncthreads();
    h_io[gi] = r / sc[1];
}

// ---------------------------------------------------------------------------
extern "C" void kernel_launch(void* const* d_in, const int* in_sizes, int n_in,
                              void* d_out, int out_size, void* d_ws, size_t ws_size,
                              hipStream_t stream)
{
    const float* h0     = 0;
    const float* adj    = 0;
    const float* act_in = 0;
    for (int i = 0; i < n_in; ++i) {
        if (in_sizes[i] == BB * NN * QQ)      h0     = (const float*)d_in[i];
        else if (in_sizes[i] == BB * NN * NN) adj    = (const float*)d_in[i];
        else if (in_sizes[i] == BB * NN)      act_in = (const float*)d_in[i];
    }
    float* out = (float*)d_out;

    char* ws = (char*)d_ws;
    size_t off = 0;
    float* ieff = (float*)(ws + off); off += (size_t)BB * NN * QQ * 4;      // 4 MB
    float* pe0 = (float*)(ws + off); off += (size_t)CHUNKS * BB * NN * 4;   // 256 KB
    float* pi0 = (float*)(ws + off); off += (size_t)CHUNKS * BB * NN * 4;
    float* pe1 = (float*)(ws + off); off += (size_t)CHUNKS * BB * NN * 4;
    float* pi1 = (float*)(ws + off); off += (size_t)CHUNKS * BB * NN * 4;
    float* sum_e0 = (float*)(ws + off); off += (size_t)BB * NN * 4;
    float* sum_i0 = (float*)(ws + off); off += (size_t)BB * NN * 4;
    float* sum_e1 = (float*)(ws + off); off += (size_t)BB * NN * 4;
    float* sum_i1 = (float*)(ws + off); off += (size_t)BB * NN * 4;

    const size_t slice_sz = (size_t)BB * NN * QQ;

    colsum_part<<<dim3(NN / 256, CHUNKS, BB), 256, 0, stream>>>(
        adj, act_in, pe0, pi0, pe1, pi1);
    colsum_combine<<<dim3(BB * NN / 256), 256, 0, stream>>>(
        pe0, pi0, pe1, pi1, sum_e0, sum_i0, sum_e1, sum_i1);

    for (int it = 0; it < NUM_ITERS; ++it) {
        const float* h_prev = (it == 0) ? h0 : (out + (size_t)(it - 1) * slice_sz);
        float* h_cur = out + (size_t)it * slice_sz;

        if (it == 0) {
            // act path: proven R7 LDS kernel
            gemm_fused<<<dim3(NN / 64, QQ / 64, BB), 512, 0, stream>>>(
                adj, h_prev, act_in, sum_e0, h_prev, h_cur, 0);
            gemm_fused<<<dim3(NN / 64, QQ / 64, BB), 512, 0, stream>>>(
                adj, h_cur, act_in, sum_i0, (const float*)0, ieff, 1);
        } else {
            // no-act path: direct register GEMM (zero LDS, plain C++)
            gemm_direct<0><<<dim3(NN / 64, QQ / 64, BB), 512, 0, stream>>>(
                adj, h_prev, sum_e1, h_prev, h_cur);
            gemm_direct<1><<<dim3(NN / 64, QQ / 64, BB), 512, 0, stream>>>(
                adj, h_cur, sum_i1, (const float*)0, ieff);
        }
        project_kernel<<<dim3(NN, BB), 256, 0, stream>>>(h_cur, ieff);
    }
}

// Round 12
// 3774.957 us; speedup vs baseline: 2.3716x; 2.3716x over previous
//
#include <hip/hip_runtime.h>

#define NUM_ITERS 15
#define BB 2
#define NN 2048
#define QQ 256
#define CHUNKS 16          // colsum n-chunks of 128 rows

// ---------------------------------------------------------------------------
// Numerical contract (matches numpy-fp32 golden; verified absmax 0.00195 —
// LOAD-BEARING, do not relax):
//  - no FMA contraction (pragma clang fp contract(off))
//  - GEMM per output element: single fp32 accumulator, strictly ascending k,
//    round(mul) then round(add), final true division by max(sum,1)
//  - row reductions over q=256: numpy pairwise tree, order replicated exactly
//  - colsum: ascending-n in 16 chunks, combined ascending
//
// R4: gfx950 VGPR max=256; uncapped bounds + big unrolls -> scratch spill.
// R5: 1 wave/SIMD latency-bound under COMPILER scheduling.
// R6: counted waitcnt regions need "memory" clobbers + sched_barrier fences.
// R7: counted-lgkm 4x2/8-wave = 141us top / ~120us avg = at the ~85 B/cyc/CU
//     LDS pipe ceiling (12288 B/kk -> 123us floor).
// R8/R9: 4-wave configs cap ~45 B/cyc regardless of depth.
// R10: asm-pinned 72-reg rotating files crash/break counted vmcnt.
// R11: plain-C++ register pipeline gets collapsed by regalloc (VGPR 56,
//     loads rematerialized at use, 338us). Both LDS-escape routes closed.
// R12 (this round): R7 structure, 64x32 tiles -> 2 INDEPENDENT blocks/CU
//     (independent barriers overlap the per-tile barrier drain, the ~18us
//     gap between R7's 141 top and the 123 floor). Same counted-lgkm asm,
//     same 48 pinned regs, same per-element chain.
// ---------------------------------------------------------------------------

typedef float f4v __attribute__((ext_vector_type(4)));
typedef float f2v __attribute__((ext_vector_type(2)));
typedef __attribute__((address_space(3))) const float4 lds_cf4;

#define DSR128(d, a, IMM) asm volatile("ds_read_b128 %0, %1 offset:" #IMM : "=v"(d) : "v"(a) : "memory")
#define DSR64(d, a, IMM)  asm volatile("ds_read_b64 %0, %1 offset:" #IMM  : "=v"(d) : "v"(a) : "memory")
#define LGKM(N)           asm volatile("s_waitcnt lgkmcnt(" #N ")" ::: "memory")

__global__ __launch_bounds__(256) void colsum_part(
    const float* __restrict__ adj, const float* __restrict__ act,
    float* __restrict__ pe0, float* __restrict__ pi0,
    float* __restrict__ pe1, float* __restrict__ pi1)
{
#pragma clang fp contract(off)
    const int b = (int)blockIdx.z;
    const int c = (int)blockIdx.y;
    const int m = (int)blockIdx.x * 256 + (int)threadIdx.x;
    const float* src = adj + (size_t)b * NN * NN;
    const float* ab  = act + (size_t)b * NN;
    float se0 = 0.0f, si0 = 0.0f, se1 = 0.0f, si1 = 0.0f;
    const int n0 = c * (NN / CHUNKS);
    for (int n = n0; n < n0 + NN / CHUNKS; ++n) {
        float x = src[(size_t)n * NN + m];
        float e = (x > 0.5f) ? x : 0.0f;
        float v = 1.0f - x;
        float iv = (v > 0.5f) ? v : 0.0f;
        float av = ab[n];
        se1 = se1 + e;
        si1 = si1 + iv;
        se0 = se0 + e * av;
        si0 = si0 + iv * av;
    }
    size_t o = ((size_t)c * BB + b) * NN + m;
    pe0[o] = se0; pi0[o] = si0; pe1[o] = se1; pi1[o] = si1;
}

__global__ __launch_bounds__(256) void colsum_combine(
    const float* __restrict__ pe0, const float* __restrict__ pi0,
    const float* __restrict__ pe1, const float* __restrict__ pi1,
    float* __restrict__ se0, float* __restrict__ si0,
    float* __restrict__ se1, float* __restrict__ si1)
{
#pragma clang fp contract(off)
    const int i = (int)blockIdx.x * 256 + (int)threadIdx.x;   // 0..BB*NN-1
    float a = 0.0f, bb = 0.0f, cc = 0.0f, dd = 0.0f;
    for (int c = 0; c < CHUNKS; ++c) {
        size_t o = (size_t)c * (BB * NN) + i;
        a  = a  + pe0[o];
        bb = bb + pi0[o];
        cc = cc + pe1[o];
        dd = dd + pi1[o];
    }
    se0[i] = a; si0[i] = bb; se1[i] = cc; si1[i] = dd;
}

// ---------------------------------------------------------------------------
// Fused thresholded GEMM, np-fp32-exact per-element chain:
//   C[m][q] = sum_k (thr(adj[k][m]) * act[k]) * hsrc[k][q]   (ascending k)
//   mode 0: dst = h_old + C/max(sum,1);  mode 1: dst = C/max(sum,1)
//
// v12: 64x32 tile, BK=64, 256 threads (4 waves), 4x2 microtile, dbuf LDS,
// counted-lgkm inner loop (R7-proven schedule: 16 groups of 4 kk, issue
// next group's 8 ds_reads, lgkmcnt(8), sched_barrier, 32 MACs).
// Grid 512 blocks = 2 independent blocks/CU (LDS 52KB x2 = 104KB fits):
// independent barriers overlap each other's staging drain.
// ---------------------------------------------------------------------------
__global__ __launch_bounds__(256, 4) void gemm_fused(
    const float* __restrict__ adj,
    const float* __restrict__ hsrc,
    const float* act,
    const float* __restrict__ sums,
    const float* h_old,
    float* __restrict__ dst,
    int mode)
{
#pragma clang fp contract(off)
    __shared__ float4 W2[2][64][17];   // [dbuf][kk][16 f4 m-cols +pad] row=272B
    __shared__ float4 H2[2][64][9];    // [dbuf][kk][8 f4 q-cols +pad]  row=144B

    const int b  = (int)blockIdx.z;
    const int m0 = (int)blockIdx.x * 64;
    const int q0 = (int)blockIdx.y * 32;
    const int tid = (int)threadIdx.x;
    const int tq  = tid & 15;      // q-group: cols q0 + tq*2 .. +1
    const int tm  = tid >> 4;      // m-group: rows m0 + tm*4 .. +3

    const float* adjb = adj + (size_t)b * NN * NN;
    const float* hb   = hsrc + (size_t)b * NN * QQ;
    const float* ab   = (act != 0) ? (act + (size_t)b * NN) : (const float*)0;

    // true LDS byte offsets via addrspace(3) pointers (32-bit)
    const unsigned wbase = (unsigned)(uintptr_t)(lds_cf4*)&W2[0][0][0] + (unsigned)tm * 16u;
    const unsigned hbase = (unsigned)(uintptr_t)(lds_cf4*)&H2[0][0][0] + (unsigned)tq * 8u;

    float acc[4][2];
    #pragma unroll
    for (int i = 0; i < 4; ++i)
        #pragma unroll
        for (int j = 0; j < 2; ++j)
            acc[i][j] = 0.0f;

    float4 wreg[4], hreg[2];

    // issue global loads for K-tile starting at kbase into regs
    auto stage_load = [&](int kbase) {
#pragma clang fp contract(off)
        #pragma unroll
        for (int j = 0; j < 4; ++j) {          // W: 64kk x 16 seg = 1024 f4
            int idx = tid + j * 256;
            int kk  = idx >> 4;                // 0..63
            int seg = idx & 15;                // 0..15
            wreg[j] = *(const float4*)(adjb + (size_t)(kbase + kk) * NN + m0 + seg * 4);
        }
        #pragma unroll
        for (int j = 0; j < 2; ++j) {          // H: 64kk x 8 seg = 512 f4
            int idx = tid + j * 256;
            int kk  = idx >> 3;                // 0..63
            int seg = idx & 7;                 // 0..7
            hreg[j] = *(const float4*)(hb + (size_t)(kbase + kk) * QQ + q0 + seg * 4);
        }
    };

    // threshold + write regs -> LDS buffer sbuf (kbase for act indexing)
    auto stage_store = [&](int sbuf, int kbase) {
#pragma clang fp contract(off)
        #pragma unroll
        for (int j = 0; j < 4; ++j) {
            int idx = tid + j * 256;
            int kk  = idx >> 4;
            int seg = idx & 15;
            float4 x = wreg[j];
            float4 w;
            if (mode == 0) {
                w.x = (x.x > 0.5f) ? x.x : 0.0f;
                w.y = (x.y > 0.5f) ? x.y : 0.0f;
                w.z = (x.z > 0.5f) ? x.z : 0.0f;
                w.w = (x.w > 0.5f) ? x.w : 0.0f;
            } else {
                float vx = 1.0f - x.x; w.x = (vx > 0.5f) ? vx : 0.0f;
                float vy = 1.0f - x.y; w.y = (vy > 0.5f) ? vy : 0.0f;
                float vz = 1.0f - x.z; w.z = (vz > 0.5f) ? vz : 0.0f;
                float vw = 1.0f - x.w; w.w = (vw > 0.5f) ? vw : 0.0f;
            }
            if (ab != 0) {
                float av = ab[kbase + kk];
                w.x = w.x * av; w.y = w.y * av; w.z = w.z * av; w.w = w.w * av;
            }
            W2[sbuf][kk][seg] = w;
        }
        #pragma unroll
        for (int j = 0; j < 2; ++j) {
            int idx = tid + j * 256;
            int kk  = idx >> 3;
            int seg = idx & 7;
            H2[sbuf][kk][seg] = hreg[j];
        }
    };

    // compute one K-tile from LDS buffer cbuf; counted-lgkm group pipeline
    // (W row stride 272B, group stride 1088B; H row 144B, group 576B)
    auto compute = [&](int cbuf) {
#pragma clang fp contract(off)
        __builtin_amdgcn_sched_barrier(0);     // fence: nothing enters region
        const unsigned wa = wbase + (unsigned)cbuf * 17408u;
        const unsigned ha = hbase + (unsigned)cbuf * 9216u;
        f4v w[2][4];
        f2v h[2][4];
        // prologue: group 0 (kk 0..3) into set 0
        DSR128(w[0][0], wa, 0);   DSR128(w[0][1], wa, 272);
        DSR128(w[0][2], wa, 544); DSR128(w[0][3], wa, 816);
        DSR64 (h[0][0], ha, 0);   DSR64 (h[0][1], ha, 144);
        DSR64 (h[0][2], ha, 288); DSR64 (h[0][3], ha, 432);
        #pragma unroll
        for (int g = 0; g < 16; ++g) {
            const int s = g & 1, sn = s ^ 1;
            if (g < 15) {
                unsigned awn = wa + (unsigned)((g + 1) * 1088);
                unsigned ahn = ha + (unsigned)((g + 1) * 576);
                DSR128(w[sn][0], awn, 0);   DSR128(w[sn][1], awn, 272);
                DSR128(w[sn][2], awn, 544); DSR128(w[sn][3], awn, 816);
                DSR64 (h[sn][0], ahn, 0);   DSR64 (h[sn][1], ahn, 144);
                DSR64 (h[sn][2], ahn, 288); DSR64 (h[sn][3], ahn, 432);
                LGKM(8);                       // prev group done, 8 in flight
            } else {
                LGKM(0);                       // tile epilogue: drain
            }
            __builtin_amdgcn_sched_barrier(0); // MACs stay below the wait
            #pragma unroll
            for (int j = 0; j < 4; ++j) {      // kk = 4g+j, ascending
                f4v wv = w[s][j];
                f2v hv = h[s][j];
                #pragma unroll
                for (int i = 0; i < 4; ++i) {
                    acc[i][0] = acc[i][0] + wv[i] * hv[0];
                    acc[i][1] = acc[i][1] + wv[i] * hv[1];
                }
            }
        }
        __builtin_amdgcn_sched_barrier(0);     // fence: nothing leaves region
    };

    // prologue: tile 0 into LDS buffer 0
    stage_load(0);
    stage_store(0, 0);
    __syncthreads();

    int cur = 0;
    #pragma clang loop unroll(disable)
    for (int k0 = 0; k0 < NN; k0 += 64) {
        const int knext = k0 + 64;
        if (knext < NN) stage_load(knext);     // VMEM issue, hidden by compute
        compute(cur);
        if (knext < NN) {
            stage_store(cur ^ 1, knext);       // writes the OTHER buffer
            __syncthreads();                   // one barrier per tile
            cur ^= 1;
        }
    }

    // epilogue: true division, optional h_old add, float2 stores
    #pragma unroll
    for (int i = 0; i < 4; ++i) {
        int row = m0 + tm * 4 + i;
        float s = sums[b * NN + row];
        if (s < 1.0f) s = 1.0f;
        float v0 = acc[i][0] / s;
        float v1 = acc[i][1] / s;
        size_t g = ((size_t)b * NN + row) * QQ + q0 + tq * 2;
        float2 o;
        if (mode == 0) {
            float2 ho = *(const float2*)(h_old + g);
            o.x = ho.x + v0; o.y = ho.y + v1;
        } else {
            o.x = v0; o.y = v1;
        }
        *(float2*)(dst + g) = o;
    }
}

// ---------------------------------------------------------------------------
// Projection + relu + L2-normalize, np-fp32-exact, in place on h_io.
// ---------------------------------------------------------------------------
__global__ __launch_bounds__(256) void project_kernel(
    float* h_io, const float* __restrict__ ieff)
{
#pragma clang fp contract(off)
    __shared__ float sp[256];
    __shared__ float sq[256];
    __shared__ float rs[32];
    __shared__ float sc[2];
    const int b = (int)blockIdx.y;
    const int m = (int)blockIdx.x;
    const int t = (int)threadIdx.x;

    size_t gi = ((size_t)b * NN + m) * QQ + t;
    float hv = h_io[gi];
    float ie = ieff[gi];

    sp[t] = hv * ie;
    sq[t] = ie * ie;
    __syncthreads();
    if (t < 32) {
        const float* a = (t < 16) ? sp : sq;
        int j = t & 7;
        int base = (t & 8) ? 128 : 0;
        float r = a[base + j];
        for (int i = 8; i < 128; i += 8) r = r + a[base + i + j];
        rs[t] = r;
    }
    __syncthreads();
    if (t == 0) {
        float d0 = ((rs[0] + rs[1]) + (rs[2] + rs[3])) + ((rs[4] + rs[5]) + (rs[6] + rs[7]));
        float d1 = ((rs[8] + rs[9]) + (rs[10] + rs[11])) + ((rs[12] + rs[13]) + (rs[14] + rs[15]));
        float dot = d0 + d1;
        float u0 = ((rs[16] + rs[17]) + (rs[18] + rs[19])) + ((rs[20] + rs[21]) + (rs[22] + rs[23]));
        float u1 = ((rs[24] + rs[25]) + (rs[26] + rs[27])) + ((rs[28] + rs[29]) + (rs[30] + rs[31]));
        float un = u0 + u1;
        sc[0] = dot / (un + 1e-12f);
    }
    __syncthreads();
    float c = sc[0];
    float tmp = c * ie;
    float h2 = hv - tmp;
    float r = (h2 > 0.0f) ? h2 : 0.0f;
    sp[t] = r * r;
    __syncthreads();
    if (t < 16) {
        int j = t & 7;
        int base = (t & 8) ? 128 : 0;
        float rr = sp[base + j];
        for (int i = 8; i < 128; i += 8) rr = rr + sp[base + i + j];
        rs[t] = rr;
    }
    __syncthreads();
    if (t == 0) {
        float n0 = ((rs[0] + rs[1]) + (rs[2] + rs[3])) + ((rs[4] + rs[5]) + (rs[6] + rs[7]));
        float n1 = ((rs[8] + rs[9]) + (rs[10] + rs[11])) + ((rs[12] + rs[13]) + (rs[14] + rs[15]));
        float nn = n0 + n1;
        float den = (float)sqrt((double)nn);
        if (den < 1e-8f) den = 1e-8f;
        sc[1] = den;
    }
    __syncthreads();
    h_io[gi] = r / sc[1];
}

// ---------------------------------------------------------------------------
extern "C" void kernel_launch(void* const* d_in, const int* in_sizes, int n_in,
                              void* d_out, int out_size, void* d_ws, size_t ws_size,
                              hipStream_t stream)
{
    const float* h0     = 0;
    const float* adj    = 0;
    const float* act_in = 0;
    for (int i = 0; i < n_in; ++i) {
        if (in_sizes[i] == BB * NN * QQ)      h0     = (const float*)d_in[i];
        else if (in_sizes[i] == BB * NN * NN) adj    = (const float*)d_in[i];
        else if (in_sizes[i] == BB * NN)      act_in = (const float*)d_in[i];
    }
    float* out = (float*)d_out;

    char* ws = (char*)d_ws;
    size_t off = 0;
    float* ieff = (float*)(ws + off); off += (size_t)BB * NN * QQ * 4;      // 4 MB
    float* pe0 = (float*)(ws + off); off += (size_t)CHUNKS * BB * NN * 4;   // 256 KB
    float* pi0 = (float*)(ws + off); off += (size_t)CHUNKS * BB * NN * 4;
    float* pe1 = (float*)(ws + off); off += (size_t)CHUNKS * BB * NN * 4;
    float* pi1 = (float*)(ws + off); off += (size_t)CHUNKS * BB * NN * 4;
    float* sum_e0 = (float*)(ws + off); off += (size_t)BB * NN * 4;
    float* sum_i0 = (float*)(ws + off); off += (size_t)BB * NN * 4;
    float* sum_e1 = (float*)(ws + off); off += (size_t)BB * NN * 4;
    float* sum_i1 = (float*)(ws + off); off += (size_t)BB * NN * 4;

    const size_t slice_sz = (size_t)BB * NN * QQ;

    colsum_part<<<dim3(NN / 256, CHUNKS, BB), 256, 0, stream>>>(
        adj, act_in, pe0, pi0, pe1, pi1);
    colsum_combine<<<dim3(BB * NN / 256), 256, 0, stream>>>(
        pe0, pi0, pe1, pi1, sum_e0, sum_i0, sum_e1, sum_i1);

    for (int it = 0; it < NUM_ITERS; ++it) {
        const float* act = (it == 0) ? act_in : (const float*)0;
        const float* se  = (it == 0) ? sum_e0 : sum_e1;
        const float* si  = (it == 0) ? sum_i0 : sum_i1;
        const float* h_prev = (it == 0) ? h0 : (out + (size_t)(it - 1) * slice_sz);
        float* h_cur = out + (size_t)it * slice_sz;

        // h_cur = h_prev + e_eff   (excite)
        gemm_fused<<<dim3(NN / 64, QQ / 32, BB), 256, 0, stream>>>(
            adj, h_prev, act, se, h_prev, h_cur, 0);
        // ieff from updated h     (inhibit)
        gemm_fused<<<dim3(NN / 64, QQ / 32, BB), 256, 0, stream>>>(
            adj, h_cur, act, si, (const float*)0, ieff, 1);
        // projection + relu + normalize (np-exact), in place
        project_kernel<<<dim3(NN, BB), 256, 0, stream>>>(h_cur, ieff);
    }
}